// Round 8
// baseline (153.304 us; speedup 1.0000x reference)
//
#include <hip/hip_runtime.h>
#include <math.h>

#define QN 128
#define SN 512
#define DN 768
#define TDN 1536
#define CN 64
#define KSPLIT 2
#define KCH 384   // 768 / KSPLIT

#define HQP_ELEMS (KSPLIT * QN * TDN)
#define HSP_ELEMS (KSPLIT * SN * TDN)
#define ZERO_ELEMS (QN * CN)

typedef short short8 __attribute__((ext_vector_type(8)));
typedef float f32x4 __attribute__((ext_vector_type(4)));

#define LDS_STRIDE 40            // gemm: 32 k + 8 pad (bf16) per row
#define PLANE (128 * LDS_STRIDE)

__device__ __forceinline__ short bf16_rtn(float x) {
    unsigned u = __float_as_uint(x);
    return (short)((u + 0x7fffu + ((u >> 16) & 1u)) >> 16);
}
__device__ __forceinline__ float bf16_tof(short s) {
    return __uint_as_float(((unsigned)(unsigned short)s) << 16);
}

// ---------------------------------------------------------------------------
// bf16x3 MFMA GEMM (unchanged from R7): split-K 2, grid (12,5,2), block 256.
// ---------------------------------------------------------------------------
__global__ __launch_bounds__(256) void gemm_kernel(
    const float* __restrict__ query, const float* __restrict__ support,
    const float* __restrict__ W1, float* __restrict__ hqp, float* __restrict__ hsp,
    float* __restrict__ zbuf, int* __restrict__ donecnt)
{
    const int nt = blockIdx.x;   // 0..11
    const int mt = blockIdx.y;   // 0..4
    const int kz = blockIdx.z;   // 0..1
    const int tid = threadIdx.x;

    if (nt == 0 && kz == 0) {    // zero aggbuf + donecnt
        int o = (mt * 256 + tid) * 8;
        if (o < ZERO_ELEMS) {
            *(float4*)&zbuf[o]     = make_float4(0.f, 0.f, 0.f, 0.f);
            *(float4*)&zbuf[o + 4] = make_float4(0.f, 0.f, 0.f, 0.f);
        }
        if (mt == 0 && tid == 0) *donecnt = 0;
    }

    const float* A;
    float* Cout;
    int M0, Koff;
    if (mt == 0) { A = query;   M0 = 0;              Koff = 0;  Cout = hqp + (size_t)kz * QN * TDN; }
    else         { A = support; M0 = (mt - 1) * 128; Koff = DN; Cout = hsp + (size_t)kz * SN * TDN; }

    __shared__ short lds[2][4][PLANE];   // [buf][Ah, Al, Bh, Bl]

    const int r  = tid >> 1;
    const int kh = (tid & 1) * 16;

    const float* Arow = &A [(size_t)(M0 + r) * DN  + kz * KCH + kh];
    const float* Brow = &W1[(size_t)(nt * 128 + r) * TDN + Koff + kz * KCH + kh];

    f32x4 acc[4][4];
    #pragma unroll
    for (int i = 0; i < 4; ++i)
        #pragma unroll
        for (int j = 0; j < 4; ++j)
            acc[i][j] = (f32x4){0.f, 0.f, 0.f, 0.f};

    auto stage = [&](short* plane, float4 v0, float4 v1, float4 v2, float4 v3) {
        float f[16] = {v0.x,v0.y,v0.z,v0.w, v1.x,v1.y,v1.z,v1.w,
                       v2.x,v2.y,v2.z,v2.w, v3.x,v3.y,v3.z,v3.w};
        short hi[16], lo[16];
        #pragma unroll
        for (int i = 0; i < 16; ++i) {
            hi[i] = bf16_rtn(f[i]);
            lo[i] = bf16_rtn(f[i] - bf16_tof(hi[i]));
        }
        short* dsth = plane + r * LDS_STRIDE + kh;
        #pragma unroll
        for (int i = 0; i < 16; ++i) dsth[i] = hi[i];
        short* dstl = plane + PLANE + r * LDS_STRIDE + kh;
        #pragma unroll
        for (int i = 0; i < 16; ++i) dstl[i] = lo[i];
    };

    {   // prologue
        float4 a0 = *(const float4*)(Arow),     a1 = *(const float4*)(Arow + 4);
        float4 a2 = *(const float4*)(Arow + 8), a3 = *(const float4*)(Arow + 12);
        float4 b0 = *(const float4*)(Brow),     b1 = *(const float4*)(Brow + 4);
        float4 b2 = *(const float4*)(Brow + 8), b3 = *(const float4*)(Brow + 12);
        stage(lds[0][0], a0, a1, a2, a3);
        stage(lds[0][2], b0, b1, b2, b3);
    }
    __syncthreads();

    const int lane  = tid & 63;
    const int w     = tid >> 6;
    const int lm    = lane & 15;
    const int quad  = lane >> 4;
    const int wrow0 = (w >> 1) * 64;
    const int wcol0 = (w & 1) * 64;

    int buf = 0;
    for (int step = 0; step < 12; ++step) {
        float4 a0, a1, a2, a3, b0, b1, b2, b3;
        if (step < 11) {
            const float* An = Arow + (step + 1) * 32;
            const float* Bn = Brow + (step + 1) * 32;
            a0 = *(const float4*)(An);     a1 = *(const float4*)(An + 4);
            a2 = *(const float4*)(An + 8); a3 = *(const float4*)(An + 12);
            b0 = *(const float4*)(Bn);     b1 = *(const float4*)(Bn + 4);
            b2 = *(const float4*)(Bn + 8); b3 = *(const float4*)(Bn + 12);
        }

        const short* Ah = lds[buf][0];
        const short* Al = lds[buf][1];
        const short* Bh = lds[buf][2];
        const short* Bl = lds[buf][3];

        short8 ah[4], al[4], bh[4], bl[4];
        #pragma unroll
        for (int mi = 0; mi < 4; ++mi) {
            int off = (wrow0 + mi * 16 + lm) * LDS_STRIDE + quad * 8;
            ah[mi] = *(const short8*)&Ah[off];
            al[mi] = *(const short8*)&Al[off];
        }
        #pragma unroll
        for (int ni = 0; ni < 4; ++ni) {
            int off = (wcol0 + ni * 16 + lm) * LDS_STRIDE + quad * 8;
            bh[ni] = *(const short8*)&Bh[off];
            bl[ni] = *(const short8*)&Bl[off];
        }
        #pragma unroll
        for (int mi = 0; mi < 4; ++mi)
            #pragma unroll
            for (int ni = 0; ni < 4; ++ni) {
                acc[mi][ni] = __builtin_amdgcn_mfma_f32_16x16x32_bf16(ah[mi], bh[ni], acc[mi][ni], 0, 0, 0);
                acc[mi][ni] = __builtin_amdgcn_mfma_f32_16x16x32_bf16(ah[mi], bl[ni], acc[mi][ni], 0, 0, 0);
                acc[mi][ni] = __builtin_amdgcn_mfma_f32_16x16x32_bf16(al[mi], bh[ni], acc[mi][ni], 0, 0, 0);
            }

        if (step < 11) {
            int nb = buf ^ 1;
            stage(lds[nb][0], a0, a1, a2, a3);
            stage(lds[nb][2], b0, b1, b2, b3);
            __syncthreads();
            buf = nb;
        }
    }

    #pragma unroll
    for (int mi = 0; mi < 4; ++mi)
        #pragma unroll
        for (int ni = 0; ni < 4; ++ni) {
            int grow = M0 + wrow0 + mi * 16 + quad * 4;
            int gcol = nt * 128 + wcol0 + ni * 16 + lm;
            #pragma unroll
            for (int rr = 0; rr < 4; ++rr)
                Cout[(size_t)(grow + rr) * TDN + gcol] = acc[mi][ni][rr];
        }
}

// ---------------------------------------------------------------------------
// Score v2: row-major XOR-swizzled LDS (no transpose => conflict-free staging
// writes; swizzle => <=2-way compute reads). grid (32, 2, 8) = 512 blocks
// (2/CU resident), block 256, micro 4x4 over a 64q x 64s tile, jc-chunk 48.
// Logical float4-group q4 of row r stored at group (q4 ^ ((r>>2)&7)),
// row stride 68 floats. Label reduce direct from registers (run-length over
// each thread's 4 s-cols). Last block (donecnt==511) runs the finale.
// ---------------------------------------------------------------------------
#define JC 48
#define SSTR 68   // floats per LDS row (16 groups worth + 4 pad)

__global__ __launch_bounds__(256) void score_kernel(
    const float* __restrict__ hqp, const float* __restrict__ hsp,
    const float* __restrict__ b1, const float* __restrict__ W2,
    const int* __restrict__ labels, const int* __restrict__ tgt,
    float* __restrict__ aggbuf, int* __restrict__ donecnt,
    float* __restrict__ out)
{
    const int jc = blockIdx.x;   // 0..31
    const int qt = blockIdx.y;   // 0..1
    const int st = blockIdx.z;   // 0..7

    __shared__ float hqL[64 * SSTR];
    __shared__ float hsL[64 * SSTR];
    __shared__ float w2s[JC];
    __shared__ int   lab[64];
    __shared__ float cnt[CN];
    __shared__ float red[2];
    __shared__ int   isLast;

    const int tid = threadIdx.x;
    if (tid < 64) lab[tid] = labels[st * 64 + tid];
    if (tid < 12) *(float4*)&w2s[tid * 4] = *(const float4*)&W2[jc * JC + tid * 4];

    // staging: 64 rows x 12 groups each for hq and hs = 1536 slots / 256 thr
    #pragma unroll
    for (int l = 0; l < 6; ++l) {
        int idx  = tid + l * 256;           // 0..1535
        int isHS = idx >= 768;
        int slot = isHS ? idx - 768 : idx;
        int row  = slot / 12;
        int q4   = slot - row * 12;
        int j    = jc * JC + q4 * 4;
        int phys = q4 ^ ((row >> 2) & 7);   // swizzle (phys < 16)
        if (!isHS) {
            float4 h0 = *(const float4*)&hqp[(size_t)(qt * 64 + row) * TDN + j];
            float4 h1 = *(const float4*)&hqp[(size_t)QN * TDN + (size_t)(qt * 64 + row) * TDN + j];
            float4 bb = *(const float4*)&b1[j];
            *(float4*)&hqL[row * SSTR + phys * 4] =
                make_float4(h0.x + h1.x + bb.x, h0.y + h1.y + bb.y,
                            h0.z + h1.z + bb.z, h0.w + h1.w + bb.w);
        } else {
            float4 g0 = *(const float4*)&hsp[(size_t)(st * 64 + row) * TDN + j];
            float4 g1 = *(const float4*)&hsp[(size_t)SN * TDN + (size_t)(st * 64 + row) * TDN + j];
            *(float4*)&hsL[row * SSTR + phys * 4] =
                make_float4(g0.x + g1.x, g0.y + g1.y, g0.z + g1.z, g0.w + g1.w);
        }
    }
    __syncthreads();

    const int tx = tid & 15;   // s-micro: cols tx*4..+3
    const int ty = tid >> 4;   // q-micro: rows ty*4..+3
    float acc[4][4];
    #pragma unroll
    for (int i = 0; i < 4; ++i)
        #pragma unroll
        for (int j = 0; j < 4; ++j) acc[i][j] = 0.0f;

    const int akey = ty & 7;
    const int bkey = tx & 7;

    for (int jj4 = 0; jj4 < 12; ++jj4) {
        float4 a4[4], b4[4];
        const int pa = (jj4 ^ akey) * 4;
        const int pb = (jj4 ^ bkey) * 4;
        #pragma unroll
        for (int i = 0; i < 4; ++i)
            a4[i] = *(const float4*)&hqL[(ty * 4 + i) * SSTR + pa];
        #pragma unroll
        for (int j = 0; j < 4; ++j)
            b4[j] = *(const float4*)&hsL[(tx * 4 + j) * SSTR + pb];
        float4 w4 = *(const float4*)&w2s[jj4 * 4];

        #pragma unroll
        for (int c = 0; c < 4; ++c) {
            float w = (c == 0) ? w4.x : (c == 1) ? w4.y : (c == 2) ? w4.z : w4.w;
            float a[4] = { (c==0)?a4[0].x:(c==1)?a4[0].y:(c==2)?a4[0].z:a4[0].w,
                           (c==0)?a4[1].x:(c==1)?a4[1].y:(c==2)?a4[1].z:a4[1].w,
                           (c==0)?a4[2].x:(c==1)?a4[2].y:(c==2)?a4[2].z:a4[2].w,
                           (c==0)?a4[3].x:(c==1)?a4[3].y:(c==2)?a4[3].z:a4[3].w };
            float b[4] = { (c==0)?b4[0].x:(c==1)?b4[0].y:(c==2)?b4[0].z:b4[0].w,
                           (c==0)?b4[1].x:(c==1)?b4[1].y:(c==2)?b4[1].z:b4[1].w,
                           (c==0)?b4[2].x:(c==1)?b4[2].y:(c==2)?b4[2].z:b4[2].w,
                           (c==0)?b4[3].x:(c==1)?b4[3].y:(c==2)?b4[3].z:b4[3].w };
            #pragma unroll
            for (int i = 0; i < 4; ++i)
                #pragma unroll
                for (int j = 0; j < 4; ++j)
                    acc[i][j] += w * fmaxf(a[i] + b[j], 0.0f);
        }
    }

    // label reduce direct from registers: run-length over this thread's 4 s
    {
        const int l0 = lab[tx * 4 + 0], l1 = lab[tx * 4 + 1];
        const int l2 = lab[tx * 4 + 2], l3 = lab[tx * 4 + 3];
        #pragma unroll
        for (int i = 0; i < 4; ++i) {
            float* aggrow = aggbuf + (size_t)(qt * 64 + ty * 4 + i) * CN;
            float runv = acc[i][0];
            int   runc = l0;
            if (l1 != runc) { atomicAdd(&aggrow[runc], runv); runv = 0.0f; runc = l1; }
            runv += acc[i][1];
            if (l2 != runc) { atomicAdd(&aggrow[runc], runv); runv = 0.0f; runc = l2; }
            runv += acc[i][2];
            if (l3 != runc) { atomicAdd(&aggrow[runc], runv); runv = 0.0f; runc = l3; }
            runv += acc[i][3];
            atomicAdd(&aggrow[runc], runv);
        }
    }

    // -------- last-block-done finale --------
    __syncthreads();
    if (tid == 0) {
        __threadfence();
        isLast = (atomicAdd(donecnt, 1) == 511);
    }
    __syncthreads();
    if (!isLast) return;
    __threadfence();

    if (tid < CN) cnt[tid] = 0.0f;
    __syncthreads();
    atomicAdd(&cnt[labels[tid]],       1.0f);
    atomicAdd(&cnt[labels[tid + 256]], 1.0f);
    __syncthreads();

    float lossv = 0.0f;
    if (tid < QN) {
        const int q = tid;
        const float* rowp = aggbuf + (size_t)q * CN;
        const int t = tgt[q];
        float best = -1e30f, vt = 0.0f;
        int bi = 0;
        #pragma unroll
        for (int c = 0; c < CN; ++c) {
            float v = __hip_atomic_load(&rowp[c], __ATOMIC_RELAXED,
                                        __HIP_MEMORY_SCOPE_AGENT)
                      / fmaxf(cnt[c], 1.0f);
            if (v > best) { best = v; bi = c; }   // lower idx wins ties
            if (c == t) vt = v;
        }
        float e = 0.0f;
        #pragma unroll
        for (int c = 0; c < CN; ++c) {
            float v = __hip_atomic_load(&rowp[c], __ATOMIC_RELAXED,
                                        __HIP_MEMORY_SCOPE_AGENT)
                      / fmaxf(cnt[c], 1.0f);
            e += expf(v - best);
        }
        out[1 + q] = (bi == t) ? 1.0f : 0.0f;
        lossv = -(vt - best - logf(e));
    }
    #pragma unroll
    for (int off = 1; off < 64; off <<= 1)
        lossv += __shfl_xor(lossv, off);
    if ((tid & 63) == 0) red[tid >> 6] = lossv;
    __syncthreads();
    if (tid == 0) out[0] = (red[0] + red[1]) / (float)QN;
}

extern "C" void kernel_launch(void* const* d_in, const int* in_sizes, int n_in,
                              void* d_out, int out_size, void* d_ws, size_t ws_size,
                              hipStream_t stream) {
    const float* query   = (const float*)d_in[0];
    const float* support = (const float*)d_in[1];
    const float* W1      = (const float*)d_in[2];
    const float* b1      = (const float*)d_in[3];
    const float* W2      = (const float*)d_in[4];
    // d_in[5] = b2: uniform shift, cancels under log_softmax/argmax -> unused
    const int* labels = (const int*)d_in[6];
    const int* tgt    = (const int*)d_in[7];

    float* ws      = (float*)d_ws;
    float* hqp     = ws;
    float* hsp     = hqp + HQP_ELEMS;
    float* aggbuf  = hsp + HSP_ELEMS;
    int*   donecnt = (int*)(aggbuf + QN * CN);
    float* out     = (float*)d_out;

    hipLaunchKernelGGL(gemm_kernel, dim3(12, 5, 2), dim3(256), 0, stream,
                       query, support, W1, hqp, hsp, aggbuf, donecnt);
    hipLaunchKernelGGL(score_kernel, dim3(32, 2, 8), dim3(256), 0, stream,
                       hqp, hsp, b1, W2, labels, tgt, aggbuf, donecnt, out);
}

// Round 9
// 139.181 us; speedup vs baseline: 1.1015x; 1.1015x over previous
//
#include <hip/hip_runtime.h>
#include <math.h>

#define QN 128
#define SN 512
#define DN 768
#define TDN 1536
#define CN 64
#define KSPLIT 2
#define KCH 384   // 768 / KSPLIT

#define HQP_ELEMS (KSPLIT * QN * TDN)
#define HSP_ELEMS (KSPLIT * SN * TDN)
#define ZERO_ELEMS (QN * CN)

typedef short short8 __attribute__((ext_vector_type(8)));
typedef float f32x4 __attribute__((ext_vector_type(4)));

#define LDS_STRIDE 40            // gemm: 32 k + 8 pad (bf16) per row
#define PLANE (128 * LDS_STRIDE)

__device__ __forceinline__ short bf16_rtn(float x) {
    unsigned u = __float_as_uint(x);
    return (short)((u + 0x7fffu + ((u >> 16) & 1u)) >> 16);
}
__device__ __forceinline__ float bf16_tof(short s) {
    return __uint_as_float(((unsigned)(unsigned short)s) << 16);
}

// ---------------------------------------------------------------------------
// bf16x3 MFMA GEMM (stable since R5): split-K 2, grid (12,5,2), block 256.
// (nt==0,kz==0) blocks also zero aggbuf + out[0].
// ---------------------------------------------------------------------------
__global__ __launch_bounds__(256) void gemm_kernel(
    const float* __restrict__ query, const float* __restrict__ support,
    const float* __restrict__ W1, float* __restrict__ hqp, float* __restrict__ hsp,
    float* __restrict__ zbuf, float* __restrict__ out)
{
    const int nt = blockIdx.x;   // 0..11
    const int mt = blockIdx.y;   // 0..4
    const int kz = blockIdx.z;   // 0..1
    const int tid = threadIdx.x;

    if (nt == 0 && kz == 0) {    // zero aggbuf; one thread zeroes out[0]
        int o = (mt * 256 + tid) * 8;
        if (o < ZERO_ELEMS) {
            *(float4*)&zbuf[o]     = make_float4(0.f, 0.f, 0.f, 0.f);
            *(float4*)&zbuf[o + 4] = make_float4(0.f, 0.f, 0.f, 0.f);
        }
        if (mt == 0 && tid == 0) out[0] = 0.0f;
    }

    const float* A;
    float* Cout;
    int M0, Koff;
    if (mt == 0) { A = query;   M0 = 0;              Koff = 0;  Cout = hqp + (size_t)kz * QN * TDN; }
    else         { A = support; M0 = (mt - 1) * 128; Koff = DN; Cout = hsp + (size_t)kz * SN * TDN; }

    __shared__ short lds[2][4][PLANE];   // [buf][Ah, Al, Bh, Bl]

    const int r  = tid >> 1;
    const int kh = (tid & 1) * 16;

    const float* Arow = &A [(size_t)(M0 + r) * DN  + kz * KCH + kh];
    const float* Brow = &W1[(size_t)(nt * 128 + r) * TDN + Koff + kz * KCH + kh];

    f32x4 acc[4][4];
    #pragma unroll
    for (int i = 0; i < 4; ++i)
        #pragma unroll
        for (int j = 0; j < 4; ++j)
            acc[i][j] = (f32x4){0.f, 0.f, 0.f, 0.f};

    auto stage = [&](short* plane, float4 v0, float4 v1, float4 v2, float4 v3) {
        float f[16] = {v0.x,v0.y,v0.z,v0.w, v1.x,v1.y,v1.z,v1.w,
                       v2.x,v2.y,v2.z,v2.w, v3.x,v3.y,v3.z,v3.w};
        short hi[16], lo[16];
        #pragma unroll
        for (int i = 0; i < 16; ++i) {
            hi[i] = bf16_rtn(f[i]);
            lo[i] = bf16_rtn(f[i] - bf16_tof(hi[i]));
        }
        short* dsth = plane + r * LDS_STRIDE + kh;
        #pragma unroll
        for (int i = 0; i < 16; ++i) dsth[i] = hi[i];
        short* dstl = plane + PLANE + r * LDS_STRIDE + kh;
        #pragma unroll
        for (int i = 0; i < 16; ++i) dstl[i] = lo[i];
    };

    {   // prologue
        float4 a0 = *(const float4*)(Arow),     a1 = *(const float4*)(Arow + 4);
        float4 a2 = *(const float4*)(Arow + 8), a3 = *(const float4*)(Arow + 12);
        float4 b0 = *(const float4*)(Brow),     b1 = *(const float4*)(Brow + 4);
        float4 b2 = *(const float4*)(Brow + 8), b3 = *(const float4*)(Brow + 12);
        stage(lds[0][0], a0, a1, a2, a3);
        stage(lds[0][2], b0, b1, b2, b3);
    }
    __syncthreads();

    const int lane  = tid & 63;
    const int w     = tid >> 6;
    const int lm    = lane & 15;
    const int quad  = lane >> 4;
    const int wrow0 = (w >> 1) * 64;
    const int wcol0 = (w & 1) * 64;

    int buf = 0;
    for (int step = 0; step < 12; ++step) {
        float4 a0, a1, a2, a3, b0, b1, b2, b3;
        if (step < 11) {
            const float* An = Arow + (step + 1) * 32;
            const float* Bn = Brow + (step + 1) * 32;
            a0 = *(const float4*)(An);     a1 = *(const float4*)(An + 4);
            a2 = *(const float4*)(An + 8); a3 = *(const float4*)(An + 12);
            b0 = *(const float4*)(Bn);     b1 = *(const float4*)(Bn + 4);
            b2 = *(const float4*)(Bn + 8); b3 = *(const float4*)(Bn + 12);
        }

        const short* Ah = lds[buf][0];
        const short* Al = lds[buf][1];
        const short* Bh = lds[buf][2];
        const short* Bl = lds[buf][3];

        short8 ah[4], al[4], bh[4], bl[4];
        #pragma unroll
        for (int mi = 0; mi < 4; ++mi) {
            int off = (wrow0 + mi * 16 + lm) * LDS_STRIDE + quad * 8;
            ah[mi] = *(const short8*)&Ah[off];
            al[mi] = *(const short8*)&Al[off];
        }
        #pragma unroll
        for (int ni = 0; ni < 4; ++ni) {
            int off = (wcol0 + ni * 16 + lm) * LDS_STRIDE + quad * 8;
            bh[ni] = *(const short8*)&Bh[off];
            bl[ni] = *(const short8*)&Bl[off];
        }
        #pragma unroll
        for (int mi = 0; mi < 4; ++mi)
            #pragma unroll
            for (int ni = 0; ni < 4; ++ni) {
                acc[mi][ni] = __builtin_amdgcn_mfma_f32_16x16x32_bf16(ah[mi], bh[ni], acc[mi][ni], 0, 0, 0);
                acc[mi][ni] = __builtin_amdgcn_mfma_f32_16x16x32_bf16(ah[mi], bl[ni], acc[mi][ni], 0, 0, 0);
                acc[mi][ni] = __builtin_amdgcn_mfma_f32_16x16x32_bf16(al[mi], bh[ni], acc[mi][ni], 0, 0, 0);
            }

        if (step < 11) {
            int nb = buf ^ 1;
            stage(lds[nb][0], a0, a1, a2, a3);
            stage(lds[nb][2], b0, b1, b2, b3);
            __syncthreads();
            buf = nb;
        }
    }

    #pragma unroll
    for (int mi = 0; mi < 4; ++mi)
        #pragma unroll
        for (int ni = 0; ni < 4; ++ni) {
            int grow = M0 + wrow0 + mi * 16 + quad * 4;
            int gcol = nt * 128 + wcol0 + ni * 16 + lm;
            #pragma unroll
            for (int rr = 0; rr < 4; ++rr)
                Cout[(size_t)(grow + rr) * TDN + gcol] = acc[mi][ni][rr];
        }
}

// ---------------------------------------------------------------------------
// Score v3: R8's swizzled layout, NO fence / NO fused finale (proven +20 us
// regression in R7/R8). LDS 35 KB -> 4 blocks/CU (16 waves). Atomics drain
// overlapped with kernel retirement + next launch.
// grid (32, 2, 8) = 512 blocks; jc chunk 48; micro 4x4 over 64q x 64s.
// ---------------------------------------------------------------------------
#define JC 48
#define SSTR 68

__global__ __launch_bounds__(256) void score_kernel(
    const float* __restrict__ hqp, const float* __restrict__ hsp,
    const float* __restrict__ b1, const float* __restrict__ W2,
    const int* __restrict__ labels, float* __restrict__ aggbuf)
{
    const int jc = blockIdx.x;   // 0..31
    const int qt = blockIdx.y;   // 0..1
    const int st = blockIdx.z;   // 0..7

    __shared__ float hqL[64 * SSTR];
    __shared__ float hsL[64 * SSTR];
    __shared__ float w2s[JC];
    __shared__ int   lab[64];

    const int tid = threadIdx.x;
    if (tid < 64) lab[tid] = labels[st * 64 + tid];
    if (tid < 12) *(float4*)&w2s[tid * 4] = *(const float4*)&W2[jc * JC + tid * 4];

    #pragma unroll
    for (int l = 0; l < 6; ++l) {
        int idx  = tid + l * 256;           // 0..1535
        int isHS = idx >= 768;
        int slot = isHS ? idx - 768 : idx;
        int row  = slot / 12;
        int q4   = slot - row * 12;
        int j    = jc * JC + q4 * 4;
        int phys = q4 ^ ((row >> 2) & 7);   // swizzle (q4<12 keeps phys<16)
        if (!isHS) {
            float4 h0 = *(const float4*)&hqp[(size_t)(qt * 64 + row) * TDN + j];
            float4 h1 = *(const float4*)&hqp[(size_t)QN * TDN + (size_t)(qt * 64 + row) * TDN + j];
            float4 bb = *(const float4*)&b1[j];
            *(float4*)&hqL[row * SSTR + phys * 4] =
                make_float4(h0.x + h1.x + bb.x, h0.y + h1.y + bb.y,
                            h0.z + h1.z + bb.z, h0.w + h1.w + bb.w);
        } else {
            float4 g0 = *(const float4*)&hsp[(size_t)(st * 64 + row) * TDN + j];
            float4 g1 = *(const float4*)&hsp[(size_t)SN * TDN + (size_t)(st * 64 + row) * TDN + j];
            *(float4*)&hsL[row * SSTR + phys * 4] =
                make_float4(g0.x + g1.x, g0.y + g1.y, g0.z + g1.z, g0.w + g1.w);
        }
    }
    __syncthreads();

    const int tx = tid & 15;   // s-micro: cols tx*4..+3
    const int ty = tid >> 4;   // q-micro: rows ty*4..+3
    float acc[4][4];
    #pragma unroll
    for (int i = 0; i < 4; ++i)
        #pragma unroll
        for (int j = 0; j < 4; ++j) acc[i][j] = 0.0f;

    const int akey = ty & 7;
    const int bkey = tx & 7;

    for (int jj4 = 0; jj4 < 12; ++jj4) {
        float4 a4[4], b4[4];
        const int pa = (jj4 ^ akey) * 4;
        const int pb = (jj4 ^ bkey) * 4;
        #pragma unroll
        for (int i = 0; i < 4; ++i)
            a4[i] = *(const float4*)&hqL[(ty * 4 + i) * SSTR + pa];
        #pragma unroll
        for (int j = 0; j < 4; ++j)
            b4[j] = *(const float4*)&hsL[(tx * 4 + j) * SSTR + pb];
        float4 w4 = *(const float4*)&w2s[jj4 * 4];

        #pragma unroll
        for (int c = 0; c < 4; ++c) {
            float w = (c == 0) ? w4.x : (c == 1) ? w4.y : (c == 2) ? w4.z : w4.w;
            float a[4] = { (c==0)?a4[0].x:(c==1)?a4[0].y:(c==2)?a4[0].z:a4[0].w,
                           (c==0)?a4[1].x:(c==1)?a4[1].y:(c==2)?a4[1].z:a4[1].w,
                           (c==0)?a4[2].x:(c==1)?a4[2].y:(c==2)?a4[2].z:a4[2].w,
                           (c==0)?a4[3].x:(c==1)?a4[3].y:(c==2)?a4[3].z:a4[3].w };
            float b[4] = { (c==0)?b4[0].x:(c==1)?b4[0].y:(c==2)?b4[0].z:b4[0].w,
                           (c==0)?b4[1].x:(c==1)?b4[1].y:(c==2)?b4[1].z:b4[1].w,
                           (c==0)?b4[2].x:(c==1)?b4[2].y:(c==2)?b4[2].z:b4[2].w,
                           (c==0)?b4[3].x:(c==1)?b4[3].y:(c==2)?b4[3].z:b4[3].w };
            #pragma unroll
            for (int i = 0; i < 4; ++i)
                #pragma unroll
                for (int j = 0; j < 4; ++j)
                    acc[i][j] += w * fmaxf(a[i] + b[j], 0.0f);
        }
    }

    // run-length label reduce over this thread's 4 s-cols, then fire-and-
    // forget global atomics (no fence, no tail work — retire immediately).
    {
        const int l0 = lab[tx * 4 + 0], l1 = lab[tx * 4 + 1];
        const int l2 = lab[tx * 4 + 2], l3 = lab[tx * 4 + 3];
        #pragma unroll
        for (int i = 0; i < 4; ++i) {
            float* aggrow = aggbuf + (size_t)(qt * 64 + ty * 4 + i) * CN;
            float runv = acc[i][0];
            int   runc = l0;
            if (l1 != runc) { atomicAdd(&aggrow[runc], runv); runv = 0.0f; runc = l1; }
            runv += acc[i][1];
            if (l2 != runc) { atomicAdd(&aggrow[runc], runv); runv = 0.0f; runc = l2; }
            runv += acc[i][2];
            if (l3 != runc) { atomicAdd(&aggrow[runc], runv); runv = 0.0f; runc = l3; }
            runv += acc[i][3];
            atomicAdd(&aggrow[runc], runv);
        }
    }
}

// ---------------------------------------------------------------------------
// Finale (separate kernel, R5-proven): grid 32 x 256 — one wave per query.
// Counts histogram in LDS; per-wave mean, fused max+argmax, exp-sum; lane0
// writes pred flag and atomicAdds -logp/QN into out[0] (zeroed by gemm).
// ---------------------------------------------------------------------------
__global__ __launch_bounds__(256) void finale_kernel(
    const float* __restrict__ aggbuf, const int* __restrict__ labels,
    const int* __restrict__ tgt, float* __restrict__ out)
{
    __shared__ float cnt[CN];
    const int tid = threadIdx.x;
    if (tid < CN) cnt[tid] = 0.0f;
    __syncthreads();
    atomicAdd(&cnt[labels[tid]],       1.0f);
    atomicAdd(&cnt[labels[tid + 256]], 1.0f);
    __syncthreads();

    const int lane = tid & 63;
    const int q    = blockIdx.x * 4 + (tid >> 6);

    float v = aggbuf[(size_t)q * CN + lane] / fmaxf(cnt[lane], 1.0f);
    float av = v; int am = lane;
    #pragma unroll
    for (int off = 1; off < 64; off <<= 1) {
        float ov = __shfl_xor(av, off);
        int   oi = __shfl_xor(am, off);
        if (ov > av || (ov == av && oi < am)) { av = ov; am = oi; }
    }
    float m = av;
    float e = expf(v - m);
    #pragma unroll
    for (int off = 1; off < 64; off <<= 1)
        e += __shfl_xor(e, off);
    int t = tgt[q];
    float vt = __shfl(v, t, 64);
    if (lane == 0) {
        out[1 + q] = (am == t) ? 1.0f : 0.0f;
        atomicAdd(&out[0], -(vt - m - logf(e)) / (float)QN);
    }
}

extern "C" void kernel_launch(void* const* d_in, const int* in_sizes, int n_in,
                              void* d_out, int out_size, void* d_ws, size_t ws_size,
                              hipStream_t stream) {
    const float* query   = (const float*)d_in[0];
    const float* support = (const float*)d_in[1];
    const float* W1      = (const float*)d_in[2];
    const float* b1      = (const float*)d_in[3];
    const float* W2      = (const float*)d_in[4];
    // d_in[5] = b2: uniform shift, cancels under log_softmax/argmax -> unused
    const int* labels = (const int*)d_in[6];
    const int* tgt    = (const int*)d_in[7];

    float* ws     = (float*)d_ws;
    float* hqp    = ws;
    float* hsp    = hqp + HQP_ELEMS;
    float* aggbuf = hsp + HSP_ELEMS;
    float* out    = (float*)d_out;

    hipLaunchKernelGGL(gemm_kernel, dim3(12, 5, 2), dim3(256), 0, stream,
                       query, support, W1, hqp, hsp, aggbuf, out);
    hipLaunchKernelGGL(score_kernel, dim3(32, 2, 8), dim3(256), 0, stream,
                       hqp, hsp, b1, W2, labels, aggbuf);
    hipLaunchKernelGGL(finale_kernel, dim3(32), dim3(256), 0, stream,
                       aggbuf, labels, tgt, out);
}

// Round 10
// 123.662 us; speedup vs baseline: 1.2397x; 1.1255x over previous
//
#include <hip/hip_runtime.h>
#include <math.h>

#define QN 128
#define SN 512
#define DN 768
#define TDN 1536
#define CN 64
#define KSPLIT 2
#define KCH 384   // 768 / KSPLIT

#define HQP_ELEMS (KSPLIT * QN * TDN)
#define HSP_ELEMS (KSPLIT * SN * TDN)
#define ZERO_ELEMS (QN * CN)

typedef short short8 __attribute__((ext_vector_type(8)));
typedef float f32x4 __attribute__((ext_vector_type(4)));

#define ASTR 40               // shorts per LDS row (32 k + 8 pad)
#define APLANE (128 * ASTR)   // 5120 shorts
#define BPLANE (64 * ASTR)    // 2560 shorts
#define BUFSZ (2 * APLANE + 2 * BPLANE)   // 15360 shorts per buffer

__device__ __forceinline__ short bf16_rtn(float x) {
    unsigned u = __float_as_uint(x);
    return (short)((u + 0x7fffu + ((u >> 16) & 1u)) >> 16);
}
__device__ __forceinline__ float bf16_tof(short s) {
    return __uint_as_float(((unsigned)(unsigned short)s) << 16);
}

// ---------------------------------------------------------------------------
// bf16x3 MFMA GEMM: 128x64 tiles, grid (24, 5, 2) = 240 blocks (R5-level
// parallelism at KSPLIT=2). Block 256 = 4 waves; wave w owns rows w*32..+31
// as 2x4 subtiles of 16x16x32 MFMA (3 MFMAs per pair, ~2^-18 rel err).
// (nt==0,kz==0) blocks also zero aggbuf + out[0].
// ---------------------------------------------------------------------------
__global__ __launch_bounds__(256) void gemm_kernel(
    const float* __restrict__ query, const float* __restrict__ support,
    const float* __restrict__ W1, float* __restrict__ hqp, float* __restrict__ hsp,
    float* __restrict__ zbuf, float* __restrict__ out)
{
    const int nt = blockIdx.x;   // 0..23 (n-chunk 64)
    const int mt = blockIdx.y;   // 0..4
    const int kz = blockIdx.z;   // 0..1
    const int tid = threadIdx.x;

    if (nt == 0 && kz == 0) {    // zero aggbuf; one thread zeroes out[0]
        int o = (mt * 256 + tid) * 8;
        if (o < ZERO_ELEMS) {
            *(float4*)&zbuf[o]     = make_float4(0.f, 0.f, 0.f, 0.f);
            *(float4*)&zbuf[o + 4] = make_float4(0.f, 0.f, 0.f, 0.f);
        }
        if (mt == 0 && tid == 0) out[0] = 0.0f;
    }

    const float* A;
    float* Cout;
    int M0, Koff;
    if (mt == 0) { A = query;   M0 = 0;              Koff = 0;  Cout = hqp + (size_t)kz * QN * TDN; }
    else         { A = support; M0 = (mt - 1) * 128; Koff = DN; Cout = hsp + (size_t)kz * SN * TDN; }
    const int N0 = nt * 64;

    __shared__ short lds[2][BUFSZ];   // [Ah | Al | Bh | Bl]

    const int ra  = tid >> 1;          // A staging row 0..127
    const int kha = (tid & 1) * 16;    // A k-offset 0/16
    const int rb  = tid >> 2;          // B staging row 0..63
    const int khb = (tid & 3) * 8;     // B k-offset 0/8/16/24

    const float* Arow = &A [(size_t)(M0 + ra) * DN  + kz * KCH + kha];
    const float* Brow = &W1[(size_t)(N0 + rb) * TDN + Koff + kz * KCH + khb];

    f32x4 acc[2][4];
    #pragma unroll
    for (int i = 0; i < 2; ++i)
        #pragma unroll
        for (int j = 0; j < 4; ++j)
            acc[i][j] = (f32x4){0.f, 0.f, 0.f, 0.f};

    auto stageA = [&](short* base, float4 v0, float4 v1, float4 v2, float4 v3) {
        float f[16] = {v0.x,v0.y,v0.z,v0.w, v1.x,v1.y,v1.z,v1.w,
                       v2.x,v2.y,v2.z,v2.w, v3.x,v3.y,v3.z,v3.w};
        short* dh = base + ra * ASTR + kha;
        short* dl = dh + APLANE;
        #pragma unroll
        for (int i = 0; i < 16; ++i) {
            short h = bf16_rtn(f[i]);
            dh[i] = h;
            dl[i] = bf16_rtn(f[i] - bf16_tof(h));
        }
    };
    auto stageB = [&](short* base, float4 v0, float4 v1) {
        float f[8] = {v0.x,v0.y,v0.z,v0.w, v1.x,v1.y,v1.z,v1.w};
        short* dh = base + 2 * APLANE + rb * ASTR + khb;
        short* dl = dh + BPLANE;
        #pragma unroll
        for (int i = 0; i < 8; ++i) {
            short h = bf16_rtn(f[i]);
            dh[i] = h;
            dl[i] = bf16_rtn(f[i] - bf16_tof(h));
        }
    };

    {   // prologue: stage step 0 into buf 0
        float4 a0 = *(const float4*)(Arow),     a1 = *(const float4*)(Arow + 4);
        float4 a2 = *(const float4*)(Arow + 8), a3 = *(const float4*)(Arow + 12);
        float4 b0 = *(const float4*)(Brow),     b1 = *(const float4*)(Brow + 4);
        stageA(lds[0], a0, a1, a2, a3);
        stageB(lds[0], b0, b1);
    }
    __syncthreads();

    const int lane = tid & 63;
    const int w    = tid >> 6;
    const int lm   = lane & 15;
    const int quad = lane >> 4;
    const int wr0  = w * 32;

    int buf = 0;
    for (int step = 0; step < 12; ++step) {
        float4 a0, a1, a2, a3, b0, b1;
        if (step < 11) {
            const float* An = Arow + (step + 1) * 32;
            const float* Bn = Brow + (step + 1) * 32;
            a0 = *(const float4*)(An);     a1 = *(const float4*)(An + 4);
            a2 = *(const float4*)(An + 8); a3 = *(const float4*)(An + 12);
            b0 = *(const float4*)(Bn);     b1 = *(const float4*)(Bn + 4);
        }

        const short* Ah = lds[buf];
        const short* Al = Ah + APLANE;
        const short* Bh = Ah + 2 * APLANE;
        const short* Bl = Bh + BPLANE;

        short8 ah[2], al[2], bh[4], bl[4];
        #pragma unroll
        for (int mi = 0; mi < 2; ++mi) {
            int off = (wr0 + mi * 16 + lm) * ASTR + quad * 8;
            ah[mi] = *(const short8*)&Ah[off];
            al[mi] = *(const short8*)&Al[off];
        }
        #pragma unroll
        for (int ni = 0; ni < 4; ++ni) {
            int off = (ni * 16 + lm) * ASTR + quad * 8;
            bh[ni] = *(const short8*)&Bh[off];
            bl[ni] = *(const short8*)&Bl[off];
        }
        #pragma unroll
        for (int mi = 0; mi < 2; ++mi)
            #pragma unroll
            for (int ni = 0; ni < 4; ++ni) {
                acc[mi][ni] = __builtin_amdgcn_mfma_f32_16x16x32_bf16(ah[mi], bh[ni], acc[mi][ni], 0, 0, 0);
                acc[mi][ni] = __builtin_amdgcn_mfma_f32_16x16x32_bf16(ah[mi], bl[ni], acc[mi][ni], 0, 0, 0);
                acc[mi][ni] = __builtin_amdgcn_mfma_f32_16x16x32_bf16(al[mi], bh[ni], acc[mi][ni], 0, 0, 0);
            }

        if (step < 11) {
            int nb = buf ^ 1;
            stageA(lds[nb], a0, a1, a2, a3);
            stageB(lds[nb], b0, b1);
            __syncthreads();
            buf = nb;
        }
    }

    // epilogue: C/D layout col=lane&15, row=quad*4+reg (HW-verified)
    #pragma unroll
    for (int mi = 0; mi < 2; ++mi)
        #pragma unroll
        for (int ni = 0; ni < 4; ++ni) {
            int grow = M0 + wr0 + mi * 16 + quad * 4;
            int gcol = N0 + ni * 16 + lm;
            #pragma unroll
            for (int rr = 0; rr < 4; ++rr)
                Cout[(size_t)(grow + rr) * TDN + gcol] = acc[mi][ni][rr];
        }
}

// ---------------------------------------------------------------------------
// Score v4: swizzled conflict-free LDS (R9) + R5's LDS-spill 16-wide-segment
// label reduce (~200K global atomics, not 790K). No fence, no fused finale.
// grid (32, 2, 8) = 512 blocks (2/CU), block 256, micro 4x4 over 64q x 64s,
// jc chunk 48. LDS ~53 KB.
// ---------------------------------------------------------------------------
#define JC 48
#define SSTR 68

__global__ __launch_bounds__(256) void score_kernel(
    const float* __restrict__ hqp, const float* __restrict__ hsp,
    const float* __restrict__ b1, const float* __restrict__ W2,
    const int* __restrict__ labels, float* __restrict__ aggbuf)
{
    const int jc = blockIdx.x;   // 0..31
    const int qt = blockIdx.y;   // 0..1
    const int st = blockIdx.z;   // 0..7

    __shared__ float hqL[64 * SSTR];
    __shared__ float hsL[64 * SSTR];
    __shared__ float sc[64 * SSTR];
    __shared__ float w2s[JC];
    __shared__ int   lab[64];

    const int tid = threadIdx.x;
    if (tid < 64) lab[tid] = labels[st * 64 + tid];
    if (tid < 12) *(float4*)&w2s[tid * 4] = *(const float4*)&W2[jc * JC + tid * 4];

    #pragma unroll
    for (int l = 0; l < 6; ++l) {
        int idx  = tid + l * 256;           // 0..1535
        int isHS = idx >= 768;
        int slot = isHS ? idx - 768 : idx;
        int row  = slot / 12;
        int q4   = slot - row * 12;
        int j    = jc * JC + q4 * 4;
        int phys = q4 ^ ((row >> 2) & 7);   // swizzle (q4<12 keeps phys<16)
        if (!isHS) {
            float4 h0 = *(const float4*)&hqp[(size_t)(qt * 64 + row) * TDN + j];
            float4 h1 = *(const float4*)&hqp[(size_t)QN * TDN + (size_t)(qt * 64 + row) * TDN + j];
            float4 bb = *(const float4*)&b1[j];
            *(float4*)&hqL[row * SSTR + phys * 4] =
                make_float4(h0.x + h1.x + bb.x, h0.y + h1.y + bb.y,
                            h0.z + h1.z + bb.z, h0.w + h1.w + bb.w);
        } else {
            float4 g0 = *(const float4*)&hsp[(size_t)(st * 64 + row) * TDN + j];
            float4 g1 = *(const float4*)&hsp[(size_t)SN * TDN + (size_t)(st * 64 + row) * TDN + j];
            *(float4*)&hsL[row * SSTR + phys * 4] =
                make_float4(g0.x + g1.x, g0.y + g1.y, g0.z + g1.z, g0.w + g1.w);
        }
    }
    __syncthreads();

    const int tx = tid & 15;   // s-micro: cols tx*4..+3
    const int ty = tid >> 4;   // q-micro: rows ty*4..+3
    float acc[4][4];
    #pragma unroll
    for (int i = 0; i < 4; ++i)
        #pragma unroll
        for (int j = 0; j < 4; ++j) acc[i][j] = 0.0f;

    const int akey = ty & 7;
    const int bkey = tx & 7;

    for (int jj4 = 0; jj4 < 12; ++jj4) {
        float4 a4[4], b4[4];
        const int pa = (jj4 ^ akey) * 4;
        const int pb = (jj4 ^ bkey) * 4;
        #pragma unroll
        for (int i = 0; i < 4; ++i)
            a4[i] = *(const float4*)&hqL[(ty * 4 + i) * SSTR + pa];
        #pragma unroll
        for (int j = 0; j < 4; ++j)
            b4[j] = *(const float4*)&hsL[(tx * 4 + j) * SSTR + pb];
        float4 w4 = *(const float4*)&w2s[jj4 * 4];

        #pragma unroll
        for (int c = 0; c < 4; ++c) {
            float w = (c == 0) ? w4.x : (c == 1) ? w4.y : (c == 2) ? w4.z : w4.w;
            float a[4] = { (c==0)?a4[0].x:(c==1)?a4[0].y:(c==2)?a4[0].z:a4[0].w,
                           (c==0)?a4[1].x:(c==1)?a4[1].y:(c==2)?a4[1].z:a4[1].w,
                           (c==0)?a4[2].x:(c==1)?a4[2].y:(c==2)?a4[2].z:a4[2].w,
                           (c==0)?a4[3].x:(c==1)?a4[3].y:(c==2)?a4[3].z:a4[3].w };
            float b[4] = { (c==0)?b4[0].x:(c==1)?b4[0].y:(c==2)?b4[0].z:b4[0].w,
                           (c==0)?b4[1].x:(c==1)?b4[1].y:(c==2)?b4[1].z:b4[1].w,
                           (c==0)?b4[2].x:(c==1)?b4[2].y:(c==2)?b4[2].z:b4[2].w,
                           (c==0)?b4[3].x:(c==1)?b4[3].y:(c==2)?b4[3].z:b4[3].w };
            #pragma unroll
            for (int i = 0; i < 4; ++i)
                #pragma unroll
                for (int j = 0; j < 4; ++j)
                    acc[i][j] += w * fmaxf(a[i] + b[j], 0.0f);
        }
    }

    // spill tile to LDS, then 16-wide-segment run-length reduce (R5-proven:
    // ~3 global atomics per thread instead of ~6 with 4-wide segments)
    #pragma unroll
    for (int i = 0; i < 4; ++i)
        *(float4*)&sc[(ty * 4 + i) * SSTR + tx * 4] =
            make_float4(acc[i][0], acc[i][1], acc[i][2], acc[i][3]);
    __syncthreads();

    {
        int row = tid >> 2;          // 0..63
        int seg = tid & 3;           // 0..3
        float* aggrow = aggbuf + (size_t)(qt * 64 + row) * CN;
        int   runc = lab[seg * 16];
        float runv = 0.0f;
        #pragma unroll
        for (int k = 0; k < 16; ++k) {
            int s = seg * 16 + k;
            int c = lab[s];
            if (c != runc) { atomicAdd(&aggrow[runc], runv); runv = 0.0f; runc = c; }
            runv += sc[row * SSTR + s];
        }
        atomicAdd(&aggrow[runc], runv);
    }
}

// ---------------------------------------------------------------------------
// Finale: grid 32 x 256 — one wave per query. Counts histogram in LDS;
// per-wave mean, fused max+argmax, exp-sum; lane0 writes pred flag and
// atomicAdds -logp/QN into out[0] (zeroed by gemm).
// ---------------------------------------------------------------------------
__global__ __launch_bounds__(256) void finale_kernel(
    const float* __restrict__ aggbuf, const int* __restrict__ labels,
    const int* __restrict__ tgt, float* __restrict__ out)
{
    __shared__ float cnt[CN];
    const int tid = threadIdx.x;
    if (tid < CN) cnt[tid] = 0.0f;
    __syncthreads();
    atomicAdd(&cnt[labels[tid]],       1.0f);
    atomicAdd(&cnt[labels[tid + 256]], 1.0f);
    __syncthreads();

    const int lane = tid & 63;
    const int q    = blockIdx.x * 4 + (tid >> 6);

    float v = aggbuf[(size_t)q * CN + lane] / fmaxf(cnt[lane], 1.0f);
    float av = v; int am = lane;
    #pragma unroll
    for (int off = 1; off < 64; off <<= 1) {
        float ov = __shfl_xor(av, off);
        int   oi = __shfl_xor(am, off);
        if (ov > av || (ov == av && oi < am)) { av = ov; am = oi; }
    }
    float m = av;
    float e = expf(v - m);
    #pragma unroll
    for (int off = 1; off < 64; off <<= 1)
        e += __shfl_xor(e, off);
    int t = tgt[q];
    float vt = __shfl(v, t, 64);
    if (lane == 0) {
        out[1 + q] = (am == t) ? 1.0f : 0.0f;
        atomicAdd(&out[0], -(vt - m - logf(e)) / (float)QN);
    }
}

extern "C" void kernel_launch(void* const* d_in, const int* in_sizes, int n_in,
                              void* d_out, int out_size, void* d_ws, size_t ws_size,
                              hipStream_t stream) {
    const float* query   = (const float*)d_in[0];
    const float* support = (const float*)d_in[1];
    const float* W1      = (const float*)d_in[2];
    const float* b1      = (const float*)d_in[3];
    const float* W2      = (const float*)d_in[4];
    // d_in[5] = b2: uniform shift, cancels under log_softmax/argmax -> unused
    const int* labels = (const int*)d_in[6];
    const int* tgt    = (const int*)d_in[7];

    float* ws     = (float*)d_ws;
    float* hqp    = ws;
    float* hsp    = hqp + HQP_ELEMS;
    float* aggbuf = hsp + HSP_ELEMS;
    float* out    = (float*)d_out;

    hipLaunchKernelGGL(gemm_kernel, dim3(24, 5, 2), dim3(256), 0, stream,
                       query, support, W1, hqp, hsp, aggbuf, out);
    hipLaunchKernelGGL(score_kernel, dim3(32, 2, 8), dim3(256), 0, stream,
                       hqp, hsp, b1, W2, labels, aggbuf);
    hipLaunchKernelGGL(finale_kernel, dim3(32), dim3(256), 0, stream,
                       aggbuf, labels, tgt, out);
}